// Round 3
// baseline (1239.552 us; speedup 1.0000x reference)
//
#include <hip/hip_runtime.h>

#define LRELU_ALPHA 0.2f
#define NEG_INF_V  -9.0e15f

// out[bt][i][o] = elu( sum_j softmax_j( mask(lrelu(Wh1[i]+Wh2[j])) ) * Wh[j][o] )
//
// Round-3 changes vs round 2 (which still spilled ~1.6 GB of scratch: p[8][8]
// + oacc + stats exceeded the 128-VGPR budget):
//  - NO p[8][8] in registers. Two-pass softmax: pass 1 -> m[8], inv[8] only;
//    the jb loop RECOMPUTES exp(e-m)*inv per 64-j chunk and writes it straight
//    to the per-wave LDS pbuf. Peak live regs ~90 -> no spill possible.
//  - pbuf layout [8 r][68 j]: writes lane-consecutive (conflict-free; old
//    [64][8] layout caused 16-way write conflicts = the 2.16M conflict cycles),
//    reads are 4-address broadcasts on distinct banks.
//  - wh2 re-read from LDS per jb chunk (no dynamically-indexed register array).

#define FMA4(d, s, v)                          \
    d.x = fmaf(s, v.x, d.x);                   \
    d.y = fmaf(s, v.y, d.y);                   \
    d.z = fmaf(s, v.z, d.z);                   \
    d.w = fmaf(s, v.w, d.w);

__global__ __launch_bounds__(512)
void adj_bits_kernel(const float* __restrict__ adj, unsigned long long* __restrict__ bits)
{
    const int tid  = threadIdx.x;
    const int lane = tid & 63;
    const int w    = tid >> 6;
    const int g    = blockIdx.x * 8 + w;   // 0..4095
    const int row  = g >> 3;
    const int k    = g & 7;
    float v = adj[row * 512 + k * 64 + lane];
    unsigned long long m = __ballot(v > 0.f);
    if (lane == 0) bits[row * 8 + k] = m;
}

__global__ __launch_bounds__(512, 2)
void gat_fused(const float* __restrict__ h,
               const unsigned long long* __restrict__ bits,
               const float* __restrict__ W, const float* __restrict__ a,
               float* __restrict__ out)
{
    __shared__ float sWh[512 * 64];   // Wh[j][o]
    __shared__ float sWh1[512];
    __shared__ float sWh2[512];
    __shared__ float sU[64 * 68];     // phase1: hT[f][68] ; phase2: pbuf[8 waves][8r][68j]

    const int tid  = threadIdx.x;
    const int lane = tid & 63;
    const int w    = tid >> 6;          // wave id 0..7
    const int bt   = blockIdx.x;        // 0..191
    const size_t hbase = (size_t)bt * (512 * 64);

    // W column in registers: lane == o, wreg[f] = W[f][o] (phase-1 only)
    float wreg[64];
    #pragma unroll
    for (int f = 0; f < 64; ++f) wreg[f] = W[f * 64 + lane];
    const float a1v = a[lane];
    const float a2v = a[64 + lane];

    // ---------------- Phase 1: Wh = h@W, Wh1, Wh2 ----------------
    for (int c = 0; c < 8; ++c) {       // chunks of 64 nodes
        __syncthreads();                // protect sU reuse from previous chunk
        #pragma unroll
        for (int k = 0; k < 8; ++k) {
            int e = k * 512 + tid;      // e = nl*64 + f within chunk
            sU[(e & 63) * 68 + (e >> 6)] = h[hbase + (size_t)c * 4096 + e];
        }
        __syncthreads();

        float acc[8];
        #pragma unroll
        for (int r = 0; r < 8; ++r) acc[r] = 0.f;
        #pragma unroll
        for (int f = 0; f < 64; ++f) {
            float4 hA = *(const float4*)&sU[f * 68 + w * 8];     // wave-uniform broadcast
            float4 hB = *(const float4*)&sU[f * 68 + w * 8 + 4];
            float wv = wreg[f];
            acc[0] = fmaf(hA.x, wv, acc[0]);
            acc[1] = fmaf(hA.y, wv, acc[1]);
            acc[2] = fmaf(hA.z, wv, acc[2]);
            acc[3] = fmaf(hA.w, wv, acc[3]);
            acc[4] = fmaf(hB.x, wv, acc[4]);
            acc[5] = fmaf(hB.y, wv, acc[5]);
            acc[6] = fmaf(hB.z, wv, acc[6]);
            acc[7] = fmaf(hB.w, wv, acc[7]);
        }
        #pragma unroll
        for (int r = 0; r < 8; ++r) {
            int n = c * 64 + w * 8 + r;
            sWh[n * 64 + lane] = acc[r];
            float t1 = acc[r] * a1v;
            float t2 = acc[r] * a2v;
            #pragma unroll
            for (int s = 32; s > 0; s >>= 1) {
                t1 += __shfl_xor(t1, s);
                t2 += __shfl_xor(t2, s);
            }
            if (lane == 0) { sWh1[n] = t1; sWh2[n] = t2; }
        }
    }
    __syncthreads();

    // ---------------- Phase 2: softmax rows + P@Wh ----------------
    float* pbuf = &sU[w * 544];          // per-wave [8 r][68 j] (544 floats)
    const int o4 = (lane & 15) * 4;      // this lane's 4 output features
    const int jq = lane >> 4;            // j mod-4 class for the FMA loop
    const unsigned long long lmask = 1ull << lane;
    const size_t obase = (size_t)bt * 32768;

    #pragma unroll 1
    for (int rb = 0; rb < 8; ++rb) {     // wave w owns rows w*64 .. w*64+63
        const int i0 = w * 64 + rb * 8;

        float wh1[8], m[8], inv_[8];
        #pragma unroll
        for (int r = 0; r < 8; ++r) wh1[r] = sWh1[i0 + r];

        float wh2k[8];
        #pragma unroll
        for (int k = 0; k < 8; ++k) wh2k[k] = sWh2[k * 64 + lane];

        // ---- pass 1: row stats (max, 1/sum) — att[] is transient per r
        #pragma unroll
        for (int r = 0; r < 8; ++r) {
            const unsigned long long* mrow = bits + (size_t)(i0 + r) * 8;
            float att[8];
            float mx = NEG_INF_V;
            #pragma unroll
            for (int k = 0; k < 8; ++k) {
                float e = wh1[r] + wh2k[k];
                e = (e > 0.f) ? e : LRELU_ALPHA * e;
                att[k] = (mrow[k] & lmask) ? e : NEG_INF_V;
                mx = fmaxf(mx, att[k]);
            }
            #pragma unroll
            for (int s = 32; s > 0; s >>= 1) mx = fmaxf(mx, __shfl_xor(mx, s));
            float sum = 0.f;
            #pragma unroll
            for (int k = 0; k < 8; ++k) sum += __expf(att[k] - mx);
            #pragma unroll
            for (int s = 32; s > 0; s >>= 1) sum += __shfl_xor(sum, s);
            m[r] = mx;
            inv_[r] = 1.f / sum;
        }

        float4 oacc[8];
        #pragma unroll
        for (int r = 0; r < 8; ++r) oacc[r] = make_float4(0.f, 0.f, 0.f, 0.f);

        // ---- pass 2: recompute p per chunk -> pbuf -> FMA
        #pragma unroll 1
        for (int jb = 0; jb < 8; ++jb) {
            float wh2j = sWh2[jb * 64 + lane];
            const unsigned long long* mcol = bits + (size_t)i0 * 8 + jb;
            #pragma unroll
            for (int r = 0; r < 8; ++r) {
                float e = wh1[r] + wh2j;
                e = (e > 0.f) ? e : LRELU_ALPHA * e;
                float av = (mcol[r * 8] & lmask) ? e : NEG_INF_V;
                pbuf[r * 68 + lane] = __expf(av - m[r]) * inv_[r];
            }
            // same-wave DS ops are in-order: no barrier needed (pbuf is
            // private to this wave).

            #pragma unroll 2
            for (int l = 0; l < 16; ++l) {
                int jl = l * 4 + jq;
                float4 whv = *(const float4*)&sWh[(jb * 64 + jl) * 64 + o4];
                float p0 = pbuf[0 * 68 + jl];
                float p1 = pbuf[1 * 68 + jl];
                float p2 = pbuf[2 * 68 + jl];
                float p3 = pbuf[3 * 68 + jl];
                float p4 = pbuf[4 * 68 + jl];
                float p5 = pbuf[5 * 68 + jl];
                float p6 = pbuf[6 * 68 + jl];
                float p7 = pbuf[7 * 68 + jl];
                FMA4(oacc[0], p0, whv);
                FMA4(oacc[1], p1, whv);
                FMA4(oacc[2], p2, whv);
                FMA4(oacc[3], p3, whv);
                FMA4(oacc[4], p4, whv);
                FMA4(oacc[5], p5, whv);
                FMA4(oacc[6], p6, whv);
                FMA4(oacc[7], p7, whv);
            }
        }

        // ---- reduce over jq groups (lane bits 4,5), ELU, store
        #pragma unroll
        for (int r = 0; r < 8; ++r) {
            float4 v = oacc[r];
            #pragma unroll
            for (int s = 16; s <= 32; s <<= 1) {
                v.x += __shfl_xor(v.x, s);
                v.y += __shfl_xor(v.y, s);
                v.z += __shfl_xor(v.z, s);
                v.w += __shfl_xor(v.w, s);
            }
            if (jq == 0) {
                float4 res;
                res.x = (v.x > 0.f) ? v.x : __expf(v.x) - 1.f;
                res.y = (v.y > 0.f) ? v.y : __expf(v.y) - 1.f;
                res.z = (v.z > 0.f) ? v.z : __expf(v.z) - 1.f;
                res.w = (v.w > 0.f) ? v.w : __expf(v.w) - 1.f;
                *(float4*)&out[obase + (size_t)(i0 + r) * 64 + o4] = res;
            }
        }
    }
}

extern "C" void kernel_launch(void* const* d_in, const int* in_sizes, int n_in,
                              void* d_out, int out_size, void* d_ws, size_t ws_size,
                              hipStream_t stream)
{
    const float* h   = (const float*)d_in[0];   // (16,12,512,64)
    const float* adj = (const float*)d_in[1];   // (512,512)
    const float* W   = (const float*)d_in[2];   // (64,64)
    const float* a   = (const float*)d_in[3];   // (128,1)
    float* out = (float*)d_out;                 // (16,12,512,64)

    unsigned long long* bits = (unsigned long long*)d_ws;  // 512*8*8 B = 32 KB

    adj_bits_kernel<<<512, 512, 0, stream>>>(adj, bits);
    gat_fused<<<192, 512, 0, stream>>>(h, bits, W, a, out);
}